// Round 1
// baseline (1930.260 us; speedup 1.0000x reference)
//
#include <hip/hip_runtime.h>
#include <cstdint>
#include <cstddef>

// SAGE 3-layer GNN, MI355X gfx950.
// Pipeline per call: build CSR (counts -> scan -> fill), then per layer:
//   aggr = mean-neighbor(h)  [CSR gather, 1 block/node]
//   h'   = relu?(aggr @ W_l + b + h @ W_r)   [fused dual-GEMM, fp32 vector ALU]
// h2 is stored in d_out; layer-2 GEMM reads/writes d_out in place (safe:
// BN=256 => each block owns its full output rows).

#define N_NODES 100000
#define N_EDGES 1600000

// ---------------- CSR build ----------------

__global__ void count_edges(const int* __restrict__ dst, int* __restrict__ cnt) {
    int i = blockIdx.x * blockDim.x + threadIdx.x;
    if (i < N_EDGES) atomicAdd(&cnt[dst[i]], 1);
}

// One block, 1024 threads: exclusive scan of cnt[0..n-1] into row_ptr[0..n],
// and rewrite cnt[i] := row_ptr[i] so cnt becomes the fill cursor.
__global__ void scan_counts(int* __restrict__ cnt, int* __restrict__ row_ptr, int n) {
    const int T = 1024;
    int t = threadIdx.x;
    int chunk = (n + T - 1) / T;
    int beg = t * chunk;
    int end = beg + chunk; if (end > n) end = n;
    int sum = 0;
    for (int i = beg; i < end; ++i) sum += cnt[i];
    __shared__ int s[T];
    s[t] = sum;
    __syncthreads();
    for (int off = 1; off < T; off <<= 1) {
        int v = (t >= off) ? s[t - off] : 0;
        __syncthreads();
        s[t] += v;
        __syncthreads();
    }
    int running = s[t] - sum;  // exclusive prefix
    for (int i = beg; i < end; ++i) {
        int c = cnt[i];
        row_ptr[i] = running;
        cnt[i] = running;      // becomes cursor
        running += c;
    }
    if (t == T - 1) row_ptr[n] = s[T - 1];
}

__global__ void fill_csr(const int* __restrict__ src, const int* __restrict__ dst,
                         int* __restrict__ cursor, int* __restrict__ col_idx) {
    int i = blockIdx.x * blockDim.x + threadIdx.x;
    if (i < N_EDGES) {
        int p = atomicAdd(&cursor[dst[i]], 1);
        col_idx[p] = src[i];
    }
}

// ---------------- mean aggregation (CSR gather) ----------------
// grid = N_NODES blocks, blockDim = F threads (128 or 256); thread = one column.
__global__ void aggregate(const float* __restrict__ x, const int* __restrict__ row_ptr,
                          const int* __restrict__ col_idx, float* __restrict__ aggr, int F) {
    int n = blockIdx.x;
    int c = threadIdx.x;
    int b = row_ptr[n], e = row_ptr[n + 1];
    float acc0 = 0.f, acc1 = 0.f;
    int i = b;
    for (; i + 1 < e; i += 2) {
        int s0 = col_idx[i];
        int s1 = col_idx[i + 1];
        acc0 += x[(size_t)s0 * F + c];
        acc1 += x[(size_t)s1 * F + c];
    }
    if (i < e) acc0 += x[(size_t)col_idx[i] * F + c];
    float d = (float)(e - b);
    if (d < 1.f) d = 1.f;
    aggr[(size_t)n * F + c] = (acc0 + acc1) / d;
}

// ---------------- fused dual GEMM ----------------
// C[M,256] = relu?( A1[M,K] @ W1[K,256] + A2[M,K] @ W2[K,256] + bias[256] )
// Block tile: BM=64 x BN=256 (full width => in-place safe on A2==C).
// 256 threads (16x16), thread tile 4 rows x 16 cols, BK=16.
__global__ __launch_bounds__(256) void gemm_dual(
    const float* __restrict__ A1, const float* __restrict__ W1,
    const float* __restrict__ A2, const float* __restrict__ W2,
    const float* __restrict__ bias, float* __restrict__ C,
    int M, int K, int relu)
{
    __shared__ float As[16][68];    // [k][row], padded
    __shared__ float Bs[16][256];   // [k][col]
    int tid = threadIdx.x;
    int tx = tid & 15;              // col quad group
    int ty = tid >> 4;              // row quad group
    int row0 = blockIdx.x * 64;

    float acc[4][16];
    #pragma unroll
    for (int i = 0; i < 4; ++i)
        #pragma unroll
        for (int j = 0; j < 16; ++j) acc[i][j] = 0.f;

    for (int m = 0; m < 2; ++m) {
        const float* __restrict__ A = m ? A2 : A1;
        const float* __restrict__ W = m ? W2 : W1;
        for (int k0 = 0; k0 < K; k0 += 16) {
            // A tile 64x16, loaded as float4 along K, stored transposed As[k][row]
            {
                int cq = tid & 3;          // which k-quad (0..3)
                int r  = tid >> 2;         // row 0..63
                int row = row0 + r; if (row > M - 1) row = M - 1;
                float4 av = *(const float4*)&A[(size_t)row * K + (k0 + cq * 4)];
                As[cq * 4 + 0][r] = av.x;
                As[cq * 4 + 1][r] = av.y;
                As[cq * 4 + 2][r] = av.z;
                As[cq * 4 + 3][r] = av.w;
            }
            // B tile 16x256, float4 loads
            {
                int c4 = (tid & 63) * 4;
                int kr = tid >> 6;         // 0..3
                #pragma unroll
                for (int i = 0; i < 4; ++i) {
                    int kk = kr + 4 * i;
                    *(float4*)&Bs[kk][c4] = *(const float4*)&W[(size_t)(k0 + kk) * 256 + c4];
                }
            }
            __syncthreads();
            #pragma unroll
            for (int kk = 0; kk < 16; ++kk) {
                float4 av = *(const float4*)&As[kk][ty * 4];
                float a[4] = {av.x, av.y, av.z, av.w};
                #pragma unroll
                for (int jj = 0; jj < 4; ++jj) {
                    float4 bv = *(const float4*)&Bs[kk][tx * 4 + 64 * jj];
                    float bb[4] = {bv.x, bv.y, bv.z, bv.w};
                    #pragma unroll
                    for (int i = 0; i < 4; ++i)
                        #pragma unroll
                        for (int j = 0; j < 4; ++j)
                            acc[i][jj * 4 + j] += a[i] * bb[j];
                }
            }
            __syncthreads();
        }
    }

    #pragma unroll
    for (int i = 0; i < 4; ++i) {
        int row = row0 + ty * 4 + i;
        if (row >= M) continue;
        #pragma unroll
        for (int jj = 0; jj < 4; ++jj) {
            int col = tx * 4 + 64 * jj;
            float4 v;
            float* vv = (float*)&v;
            #pragma unroll
            for (int j = 0; j < 4; ++j) {
                float t = acc[i][jj * 4 + j] + bias[col + j];
                if (relu) t = fmaxf(t, 0.f);
                vv[j] = t;
            }
            *(float4*)&C[(size_t)row * 256 + col] = v;
        }
    }
}

// ---------------- launch ----------------

extern "C" void kernel_launch(void* const* d_in, const int* in_sizes, int n_in,
                              void* d_out, int out_size, void* d_ws, size_t ws_size,
                              hipStream_t stream) {
    const float* x    = (const float*)d_in[0];
    const float* W_l0 = (const float*)d_in[1];
    const float* b_l0 = (const float*)d_in[2];
    const float* W_r0 = (const float*)d_in[3];
    const float* W_l1 = (const float*)d_in[4];
    const float* b_l1 = (const float*)d_in[5];
    const float* W_r1 = (const float*)d_in[6];
    const float* W_l2 = (const float*)d_in[7];
    const float* b_l2 = (const float*)d_in[8];
    const float* W_r2 = (const float*)d_in[9];
    const int* esrc   = (const int*)d_in[10];
    const int* edst   = (const int*)d_in[11];
    float* out = (float*)d_out;

    // workspace carve-up (~212 MB total)
    size_t off = 0;
    char* ws = (char*)d_ws;
    auto take = [&](size_t bytes) -> void* {
        void* p = ws + off;
        off += (bytes + 255) & ~(size_t)255;
        return p;
    };
    int*   cnt     = (int*)take((size_t)N_NODES * 4);
    int*   row_ptr = (int*)take((size_t)(N_NODES + 1) * 4);
    int*   col_idx = (int*)take((size_t)N_EDGES * 4);
    float* aggr    = (float*)take((size_t)N_NODES * 256 * 4);
    float* h1      = (float*)take((size_t)N_NODES * 256 * 4);
    (void)ws_size; (void)in_sizes; (void)n_in; (void)out_size;

    // --- CSR build (edges are fixed but ws is re-poisoned every call) ---
    hipMemsetAsync(cnt, 0, (size_t)N_NODES * 4, stream);
    int eb = (N_EDGES + 255) / 256;
    count_edges<<<eb, 256, 0, stream>>>(edst, cnt);
    scan_counts<<<1, 1024, 0, stream>>>(cnt, row_ptr, N_NODES);
    fill_csr<<<eb, 256, 0, stream>>>(esrc, edst, cnt, col_idx);

    dim3 ggrid((N_NODES + 63) / 64, 1);

    // --- layer 0: F=128 -> 256, relu ---
    aggregate<<<N_NODES, 128, 0, stream>>>(x, row_ptr, col_idx, aggr, 128);
    gemm_dual<<<ggrid, 256, 0, stream>>>(aggr, W_l0, x, W_r0, b_l0, h1, N_NODES, 128, 1);

    // --- layer 1: 256 -> 256, relu (h2 lives in d_out) ---
    aggregate<<<N_NODES, 256, 0, stream>>>(h1, row_ptr, col_idx, aggr, 256);
    gemm_dual<<<ggrid, 256, 0, stream>>>(aggr, W_l1, h1, W_r1, b_l1, out, N_NODES, 256, 1);

    // --- layer 2: 256 -> 256, no relu, in-place on d_out ---
    aggregate<<<N_NODES, 256, 0, stream>>>(out, row_ptr, col_idx, aggr, 256);
    gemm_dual<<<ggrid, 256, 0, stream>>>(aggr, W_l2, out, W_r2, b_l2, out, N_NODES, 256, 0);
}

// Round 2
// 1172.052 us; speedup vs baseline: 1.6469x; 1.6469x over previous
//
#include <hip/hip_runtime.h>
#include <cstdint>
#include <cstddef>

// SAGE 3-layer GNN, MI355X gfx950 — round 2: bf16 MFMA GEMM + bf16 activations.
// Per call: CSR build -> convert x & weights to bf16 (Wt transposed to [N,K])
// -> per layer: bf16 gather-mean aggregate -> dual MFMA GEMM (fp32 accum),
// layers 0/1 emit bf16 activations, layer 2 emits fp32 to d_out.

#define N_NODES 100000
#define N_EDGES 1600000

typedef unsigned short ushort;
typedef unsigned int uint;
typedef __attribute__((ext_vector_type(8))) short short8;
typedef __attribute__((ext_vector_type(4))) float floatx4;

#define AS1 __attribute__((address_space(1)))
#define AS3 __attribute__((address_space(3)))

__device__ __forceinline__ float bf2f(ushort h) {
    union { uint u; float f; } c; c.u = ((uint)h) << 16; return c.f;
}
__device__ __forceinline__ ushort f2bf(float f) {
    union { float f; uint u; } c; c.f = f;
    uint u = c.u;
    return (ushort)((u + 0x7FFFu + ((u >> 16) & 1u)) >> 16);  // RTNE
}

// ---------------- CSR build ----------------

__global__ void count_edges(const int* __restrict__ dst, int* __restrict__ cnt) {
    int i = blockIdx.x * blockDim.x + threadIdx.x;
    if (i < N_EDGES) atomicAdd(&cnt[dst[i]], 1);
}

__global__ void scan_counts(int* __restrict__ cnt, int* __restrict__ row_ptr, int n) {
    const int T = 1024;
    int t = threadIdx.x;
    int chunk = (n + T - 1) / T;
    int beg = t * chunk;
    int end = beg + chunk; if (end > n) end = n;
    int sum = 0;
    for (int i = beg; i < end; ++i) sum += cnt[i];
    __shared__ int s[T];
    s[t] = sum;
    __syncthreads();
    for (int off = 1; off < T; off <<= 1) {
        int v = (t >= off) ? s[t - off] : 0;
        __syncthreads();
        s[t] += v;
        __syncthreads();
    }
    int running = s[t] - sum;
    for (int i = beg; i < end; ++i) {
        int c = cnt[i];
        row_ptr[i] = running;
        cnt[i] = running;
        running += c;
    }
    if (t == T - 1) row_ptr[n] = s[T - 1];
}

__global__ void fill_csr(const int* __restrict__ src, const int* __restrict__ dst,
                         int* __restrict__ cursor, int* __restrict__ col_idx) {
    int i = blockIdx.x * blockDim.x + threadIdx.x;
    if (i < N_EDGES) {
        int p = atomicAdd(&cursor[dst[i]], 1);
        col_idx[p] = src[i];
    }
}

// ---------------- conversions ----------------

__global__ void convert_x_bf16(const float* __restrict__ x, ushort* __restrict__ xb, int n4) {
    int i = blockIdx.x * blockDim.x + threadIdx.x;
    if (i >= n4) return;
    float4 v = *(const float4*)&x[(size_t)i * 4];
    ushort4 o;
    o.x = f2bf(v.x); o.y = f2bf(v.y); o.z = f2bf(v.z); o.w = f2bf(v.w);
    *(ushort4*)&xb[(size_t)i * 4] = o;
}

// W [K,256] f32 -> Wt [256,K] bf16 (coalesced writes, strided cached reads)
__global__ void transpose_w_bf16(const float* __restrict__ W, ushort* __restrict__ Wt, int kshift) {
    int i = blockIdx.x * blockDim.x + threadIdx.x;  // i = n*K + k
    int K = 1 << kshift;
    if (i >= 256 * K) return;
    int n = i >> kshift;
    int k = i & (K - 1);
    Wt[i] = f2bf(W[k * 256 + n]);
}

// ---------------- mean aggregation (bf16 gather, fp32 accum) ----------------
// 1 wave per node; F=256: 4 cols/thread (uint2), F=128: 2 cols/thread (uint).
__global__ __launch_bounds__(64) void aggregate_bf16(
    const ushort* __restrict__ xb, const int* __restrict__ row_ptr,
    const int* __restrict__ col_idx, ushort* __restrict__ outb, int F)
{
    int node = blockIdx.x;
    int t = threadIdx.x;
    int b = row_ptr[node], e = row_ptr[node + 1];
    float d = (float)(e - b); if (d < 1.f) d = 1.f;
    float inv = 1.f / d;

    if (F == 256) {
        int c = t * 4;
        float a0 = 0.f, a1 = 0.f, a2 = 0.f, a3 = 0.f;
        float b0 = 0.f, b1 = 0.f, b2 = 0.f, b3 = 0.f;
        int i = b;
        for (; i + 1 < e; i += 2) {
            int s0 = col_idx[i];
            int s1 = col_idx[i + 1];
            uint2 v0 = *(const uint2*)&xb[(size_t)s0 * 256 + c];
            uint2 v1 = *(const uint2*)&xb[(size_t)s1 * 256 + c];
            a0 += bf2f((ushort)(v0.x & 0xffff)); a1 += bf2f((ushort)(v0.x >> 16));
            a2 += bf2f((ushort)(v0.y & 0xffff)); a3 += bf2f((ushort)(v0.y >> 16));
            b0 += bf2f((ushort)(v1.x & 0xffff)); b1 += bf2f((ushort)(v1.x >> 16));
            b2 += bf2f((ushort)(v1.y & 0xffff)); b3 += bf2f((ushort)(v1.y >> 16));
        }
        if (i < e) {
            int s0 = col_idx[i];
            uint2 v0 = *(const uint2*)&xb[(size_t)s0 * 256 + c];
            a0 += bf2f((ushort)(v0.x & 0xffff)); a1 += bf2f((ushort)(v0.x >> 16));
            a2 += bf2f((ushort)(v0.y & 0xffff)); a3 += bf2f((ushort)(v0.y >> 16));
        }
        ushort4 o;
        o.x = f2bf((a0 + b0) * inv); o.y = f2bf((a1 + b1) * inv);
        o.z = f2bf((a2 + b2) * inv); o.w = f2bf((a3 + b3) * inv);
        *(ushort4*)&outb[(size_t)node * 256 + c] = o;
    } else {
        int c = t * 2;
        float a0 = 0.f, a1 = 0.f, b0 = 0.f, b1 = 0.f;
        int i = b;
        for (; i + 1 < e; i += 2) {
            int s0 = col_idx[i];
            int s1 = col_idx[i + 1];
            uint v0 = *(const uint*)&xb[(size_t)s0 * 128 + c];
            uint v1 = *(const uint*)&xb[(size_t)s1 * 128 + c];
            a0 += bf2f((ushort)(v0 & 0xffff)); a1 += bf2f((ushort)(v0 >> 16));
            b0 += bf2f((ushort)(v1 & 0xffff)); b1 += bf2f((ushort)(v1 >> 16));
        }
        if (i < e) {
            int s0 = col_idx[i];
            uint v0 = *(const uint*)&xb[(size_t)s0 * 128 + c];
            a0 += bf2f((ushort)(v0 & 0xffff)); a1 += bf2f((ushort)(v0 >> 16));
        }
        ushort2 o;
        o.x = f2bf((a0 + b0) * inv); o.y = f2bf((a1 + b1) * inv);
        *(ushort2*)&outb[(size_t)node * 128 + c] = o;
    }
}

// ---------------- dual MFMA GEMM ----------------
// C[M,256] = relu?( A1[M,K]@W1 + A2[M,K]@W2 + bias ), A bf16 row-major [M,K],
// W given transposed bf16 [256,K]. Block: BM=64 x BN=256, BK=32, 256 thr (4 waves).
// Wave w owns rows [w*16,w*16+16) x all 256 cols = 16 MFMA tiles of 16x16.
// LDS fragment-order layout (global_load_lds wave-uniform-base compatible):
//   As chunk (ko*64 + r)  = A[row0+r][k0+ko*8 .. +8)   (4 KB)
//   Bs chunk (ko*256 + n) = W[n][k0+ko*8 .. +8)        (16 KB)
__global__ __launch_bounds__(256) void gemm_dual_mfma(
    const ushort* __restrict__ A1, const ushort* __restrict__ W1t,
    const ushort* __restrict__ A2, const ushort* __restrict__ W2t,
    const float* __restrict__ bias, ushort* __restrict__ out_bf,
    float* __restrict__ out_f32, int M, int K, int relu)
{
    __shared__ __align__(16) ushort As[4 * 64 * 8];
    __shared__ __align__(16) ushort Bs[4 * 256 * 8];
    int tid = threadIdx.x;
    int w = tid >> 6;        // wave 0..3
    int lane = tid & 63;
    int row0 = blockIdx.x * 64;

    floatx4 acc[16];
#pragma unroll
    for (int t = 0; t < 16; ++t) acc[t] = (floatx4){0.f, 0.f, 0.f, 0.f};

    int arow = row0 + lane;
    if (arow >= M) arow = M - 1;     // clamp (dup read, stores guarded)
    int ncol = w * 64 + lane;

    int m_ = lane & 15;
    int ko = lane >> 4;

    for (int mm = 0; mm < 2; ++mm) {
        const ushort* __restrict__ A = mm ? A2 : A1;
        const ushort* __restrict__ W = mm ? W2t : W1t;
        for (int k0 = 0; k0 < K; k0 += 32) {
            // A tile: wave w stages k-chunk ko=w for all 64 rows (1 inst/wave)
            __builtin_amdgcn_global_load_lds(
                (const AS1 uint*)&A[(size_t)arow * K + k0 + w * 8],
                (AS3 uint*)&As[w * 512], 16, 0, 0);
            // B tile: 4 insts/wave, inst j stages ko=j, cols [w*64, w*64+64)
#pragma unroll
            for (int j = 0; j < 4; ++j) {
                __builtin_amdgcn_global_load_lds(
                    (const AS1 uint*)&W[(size_t)ncol * K + k0 + j * 8],
                    (AS3 uint*)&Bs[(j * 256 + w * 64) * 8], 16, 0, 0);
            }
            __syncthreads();
            short8 af = *(const short8*)&As[(ko * 64 + w * 16 + m_) * 8];
#pragma unroll
            for (int t = 0; t < 16; ++t) {
                short8 bf = *(const short8*)&Bs[(ko * 256 + t * 16 + m_) * 8];
                acc[t] = __builtin_amdgcn_mfma_f32_16x16x32_bf16(af, bf, acc[t], 0, 0, 0);
            }
            __syncthreads();
        }
    }

    // epilogue: C/D layout col=lane&15, row=(lane>>4)*4+reg
    int mq = lane >> 4;
#pragma unroll
    for (int t = 0; t < 16; ++t) {
        int col = t * 16 + m_;
        float bv = bias[col];
#pragma unroll
        for (int r = 0; r < 4; ++r) {
            int row = row0 + w * 16 + mq * 4 + r;
            if (row >= M) continue;
            float v = acc[t][r] + bv;
            if (relu) v = fmaxf(v, 0.f);
            if (out_f32) out_f32[(size_t)row * 256 + col] = v;
            else         out_bf[(size_t)row * 256 + col] = f2bf(v);
        }
    }
}

// ---------------- launch ----------------

extern "C" void kernel_launch(void* const* d_in, const int* in_sizes, int n_in,
                              void* d_out, int out_size, void* d_ws, size_t ws_size,
                              hipStream_t stream) {
    const float* x    = (const float*)d_in[0];
    const float* W_l0 = (const float*)d_in[1];
    const float* b_l0 = (const float*)d_in[2];
    const float* W_r0 = (const float*)d_in[3];
    const float* W_l1 = (const float*)d_in[4];
    const float* b_l1 = (const float*)d_in[5];
    const float* W_r1 = (const float*)d_in[6];
    const float* W_l2 = (const float*)d_in[7];
    const float* b_l2 = (const float*)d_in[8];
    const float* W_r2 = (const float*)d_in[9];
    const int* esrc   = (const int*)d_in[10];
    const int* edst   = (const int*)d_in[11];
    float* out = (float*)d_out;

    size_t off = 0;
    char* ws = (char*)d_ws;
    auto take = [&](size_t bytes) -> void* {
        void* p = ws + off;
        off += (bytes + 255) & ~(size_t)255;
        return p;
    };
    int*    cnt     = (int*)take((size_t)N_NODES * 4);
    int*    row_ptr = (int*)take((size_t)(N_NODES + 1) * 4);
    int*    col_idx = (int*)take((size_t)N_EDGES * 4);
    ushort* xb      = (ushort*)take((size_t)N_NODES * 128 * 2);
    ushort* Wl0t    = (ushort*)take((size_t)256 * 128 * 2);
    ushort* Wr0t    = (ushort*)take((size_t)256 * 128 * 2);
    ushort* Wl1t    = (ushort*)take((size_t)256 * 256 * 2);
    ushort* Wr1t    = (ushort*)take((size_t)256 * 256 * 2);
    ushort* Wl2t    = (ushort*)take((size_t)256 * 256 * 2);
    ushort* Wr2t    = (ushort*)take((size_t)256 * 256 * 2);
    ushort* aggrb   = (ushort*)take((size_t)N_NODES * 256 * 2);
    ushort* ha      = (ushort*)take((size_t)N_NODES * 256 * 2);
    ushort* hb      = (ushort*)take((size_t)N_NODES * 256 * 2);
    (void)ws_size; (void)in_sizes; (void)n_in; (void)out_size;

    // CSR
    hipMemsetAsync(cnt, 0, (size_t)N_NODES * 4, stream);
    int eb = (N_EDGES + 255) / 256;
    count_edges<<<eb, 256, 0, stream>>>(edst, cnt);
    scan_counts<<<1, 1024, 0, stream>>>(cnt, row_ptr, N_NODES);
    fill_csr<<<eb, 256, 0, stream>>>(esrc, edst, cnt, col_idx);

    // conversions
    int n4 = (N_NODES * 128) / 4;
    convert_x_bf16<<<(n4 + 255) / 256, 256, 0, stream>>>(x, xb, n4);
    transpose_w_bf16<<<(256 * 128 + 255) / 256, 256, 0, stream>>>(W_l0, Wl0t, 7);
    transpose_w_bf16<<<(256 * 128 + 255) / 256, 256, 0, stream>>>(W_r0, Wr0t, 7);
    transpose_w_bf16<<<(256 * 256 + 255) / 256, 256, 0, stream>>>(W_l1, Wl1t, 8);
    transpose_w_bf16<<<(256 * 256 + 255) / 256, 256, 0, stream>>>(W_r1, Wr1t, 8);
    transpose_w_bf16<<<(256 * 256 + 255) / 256, 256, 0, stream>>>(W_l2, Wl2t, 8);
    transpose_w_bf16<<<(256 * 256 + 255) / 256, 256, 0, stream>>>(W_r2, Wr2t, 8);

    dim3 ggrid((N_NODES + 63) / 64, 1);

    // layer 0: 128 -> 256, relu
    aggregate_bf16<<<N_NODES, 64, 0, stream>>>(xb, row_ptr, col_idx, aggrb, 128);
    gemm_dual_mfma<<<ggrid, 256, 0, stream>>>(aggrb, Wl0t, xb, Wr0t, b_l0,
                                              ha, nullptr, N_NODES, 128, 1);
    // layer 1: 256 -> 256, relu
    aggregate_bf16<<<N_NODES, 64, 0, stream>>>(ha, row_ptr, col_idx, aggrb, 256);
    gemm_dual_mfma<<<ggrid, 256, 0, stream>>>(aggrb, Wl1t, ha, Wr1t, b_l1,
                                              hb, nullptr, N_NODES, 256, 1);
    // layer 2: 256 -> 256, no relu, fp32 out
    aggregate_bf16<<<N_NODES, 64, 0, stream>>>(hb, row_ptr, col_idx, aggrb, 256);
    gemm_dual_mfma<<<ggrid, 256, 0, stream>>>(aggrb, Wl2t, hb, Wr2t, b_l2,
                                              nullptr, out, N_NODES, 256, 0);
}

// Round 3
// 965.588 us; speedup vs baseline: 1.9991x; 1.2138x over previous
//
#include <hip/hip_runtime.h>
#include <cstdint>
#include <cstddef>

// SAGE 3-layer GNN, MI355X gfx950 — round 3: parallel hierarchical CSR scan.
// (Round-2 profile: single-block scan_counts was 228 µs on one CU — replaced
// by 3-phase multi-block scan, everything else unchanged.)

#define N_NODES 100000
#define N_EDGES 1600000

#define SCAN_BLOCKS 256
#define SCAN_T 256

typedef unsigned short ushort;
typedef unsigned int uint;
typedef __attribute__((ext_vector_type(8))) short short8;
typedef __attribute__((ext_vector_type(4))) float floatx4;

#define AS1 __attribute__((address_space(1)))
#define AS3 __attribute__((address_space(3)))

__device__ __forceinline__ float bf2f(ushort h) {
    union { uint u; float f; } c; c.u = ((uint)h) << 16; return c.f;
}
__device__ __forceinline__ ushort f2bf(float f) {
    union { float f; uint u; } c; c.f = f;
    uint u = c.u;
    return (ushort)((u + 0x7FFFu + ((u >> 16) & 1u)) >> 16);  // RTNE
}

// ---------------- CSR build ----------------

__global__ void count_edges(const int* __restrict__ dst, int* __restrict__ cnt) {
    int i = blockIdx.x * blockDim.x + threadIdx.x;
    if (i < N_EDGES) atomicAdd(&cnt[dst[i]], 1);
}

// Phase 1: per-block partial sums of cnt chunks.
__global__ __launch_bounds__(SCAN_T) void scan_partial(
    const int* __restrict__ cnt, int* __restrict__ bsum, int n)
{
    int chunk = (n + SCAN_BLOCKS - 1) / SCAN_BLOCKS;
    int beg = blockIdx.x * chunk;
    int end = beg + chunk; if (end > n) end = n;
    int t = threadIdx.x;
    int s = 0;
    for (int i = beg + t; i < end; i += SCAN_T) s += cnt[i];
    __shared__ int sh[SCAN_T];
    sh[t] = s;
    __syncthreads();
    for (int off = SCAN_T / 2; off > 0; off >>= 1) {
        if (t < off) sh[t] += sh[t + off];
        __syncthreads();
    }
    if (t == 0) bsum[blockIdx.x] = sh[0];
}

// Phase 2: one tiny block exclusive-scans bsum[SCAN_BLOCKS] in place.
__global__ __launch_bounds__(SCAN_T) void scan_block_sums(int* __restrict__ bsum) {
    int t = threadIdx.x;
    __shared__ int sh[SCAN_T];
    int v = bsum[t];
    sh[t] = v;
    __syncthreads();
    for (int off = 1; off < SCAN_T; off <<= 1) {
        int u = (t >= off) ? sh[t - off] : 0;
        __syncthreads();
        sh[t] += u;
        __syncthreads();
    }
    bsum[t] = sh[t] - v;  // exclusive
}

// Phase 3: per-block local exclusive scan + block offset; writes row_ptr and
// cursor (cnt[i] := row_ptr[i]). row_ptr[n] = N_EDGES (constant).
__global__ __launch_bounds__(SCAN_T) void scan_fill(
    int* __restrict__ cnt, const int* __restrict__ bsum,
    int* __restrict__ row_ptr, int n)
{
    int chunk = (n + SCAN_BLOCKS - 1) / SCAN_BLOCKS;
    int beg = blockIdx.x * chunk;
    int end = beg + chunk; if (end > n) end = n;
    int t = threadIdx.x;
    int per = (chunk + SCAN_T - 1) / SCAN_T;
    int tb = beg + t * per;
    int te = tb + per; if (te > end) te = end;
    int s = 0;
    for (int i = tb; i < te; ++i) s += cnt[i];
    __shared__ int sh[SCAN_T];
    sh[t] = s;
    __syncthreads();
    for (int off = 1; off < SCAN_T; off <<= 1) {
        int u = (t >= off) ? sh[t - off] : 0;
        __syncthreads();
        sh[t] += u;
        __syncthreads();
    }
    int running = bsum[blockIdx.x] + sh[t] - s;  // exclusive prefix for this thread
    for (int i = tb; i < te; ++i) {
        int c = cnt[i];
        row_ptr[i] = running;
        cnt[i] = running;  // becomes fill cursor
        running += c;
    }
    if (blockIdx.x == 0 && t == 0) row_ptr[n] = N_EDGES;
}

__global__ void fill_csr(const int* __restrict__ src, const int* __restrict__ dst,
                         int* __restrict__ cursor, int* __restrict__ col_idx) {
    int i = blockIdx.x * blockDim.x + threadIdx.x;
    if (i < N_EDGES) {
        int p = atomicAdd(&cursor[dst[i]], 1);
        col_idx[p] = src[i];
    }
}

// ---------------- conversions ----------------

__global__ void convert_x_bf16(const float* __restrict__ x, ushort* __restrict__ xb, int n4) {
    int i = blockIdx.x * blockDim.x + threadIdx.x;
    if (i >= n4) return;
    float4 v = *(const float4*)&x[(size_t)i * 4];
    ushort4 o;
    o.x = f2bf(v.x); o.y = f2bf(v.y); o.z = f2bf(v.z); o.w = f2bf(v.w);
    *(ushort4*)&xb[(size_t)i * 4] = o;
}

// W [K,256] f32 -> Wt [256,K] bf16
__global__ void transpose_w_bf16(const float* __restrict__ W, ushort* __restrict__ Wt, int kshift) {
    int i = blockIdx.x * blockDim.x + threadIdx.x;  // i = n*K + k
    int K = 1 << kshift;
    if (i >= 256 * K) return;
    int n = i >> kshift;
    int k = i & (K - 1);
    Wt[i] = f2bf(W[k * 256 + n]);
}

// ---------------- mean aggregation (bf16 gather, fp32 accum) ----------------
__global__ __launch_bounds__(64) void aggregate_bf16(
    const ushort* __restrict__ xb, const int* __restrict__ row_ptr,
    const int* __restrict__ col_idx, ushort* __restrict__ outb, int F)
{
    int node = blockIdx.x;
    int t = threadIdx.x;
    int b = row_ptr[node], e = row_ptr[node + 1];
    float d = (float)(e - b); if (d < 1.f) d = 1.f;
    float inv = 1.f / d;

    if (F == 256) {
        int c = t * 4;
        float a0 = 0.f, a1 = 0.f, a2 = 0.f, a3 = 0.f;
        float b0 = 0.f, b1 = 0.f, b2 = 0.f, b3 = 0.f;
        int i = b;
        for (; i + 1 < e; i += 2) {
            int s0 = col_idx[i];
            int s1 = col_idx[i + 1];
            uint2 v0 = *(const uint2*)&xb[(size_t)s0 * 256 + c];
            uint2 v1 = *(const uint2*)&xb[(size_t)s1 * 256 + c];
            a0 += bf2f((ushort)(v0.x & 0xffff)); a1 += bf2f((ushort)(v0.x >> 16));
            a2 += bf2f((ushort)(v0.y & 0xffff)); a3 += bf2f((ushort)(v0.y >> 16));
            b0 += bf2f((ushort)(v1.x & 0xffff)); b1 += bf2f((ushort)(v1.x >> 16));
            b2 += bf2f((ushort)(v1.y & 0xffff)); b3 += bf2f((ushort)(v1.y >> 16));
        }
        if (i < e) {
            int s0 = col_idx[i];
            uint2 v0 = *(const uint2*)&xb[(size_t)s0 * 256 + c];
            a0 += bf2f((ushort)(v0.x & 0xffff)); a1 += bf2f((ushort)(v0.x >> 16));
            a2 += bf2f((ushort)(v0.y & 0xffff)); a3 += bf2f((ushort)(v0.y >> 16));
        }
        ushort4 o;
        o.x = f2bf((a0 + b0) * inv); o.y = f2bf((a1 + b1) * inv);
        o.z = f2bf((a2 + b2) * inv); o.w = f2bf((a3 + b3) * inv);
        *(ushort4*)&outb[(size_t)node * 256 + c] = o;
    } else {
        int c = t * 2;
        float a0 = 0.f, a1 = 0.f, b0 = 0.f, b1 = 0.f;
        int i = b;
        for (; i + 1 < e; i += 2) {
            int s0 = col_idx[i];
            int s1 = col_idx[i + 1];
            uint v0 = *(const uint*)&xb[(size_t)s0 * 128 + c];
            uint v1 = *(const uint*)&xb[(size_t)s1 * 128 + c];
            a0 += bf2f((ushort)(v0 & 0xffff)); a1 += bf2f((ushort)(v0 >> 16));
            b0 += bf2f((ushort)(v1 & 0xffff)); b1 += bf2f((ushort)(v1 >> 16));
        }
        if (i < e) {
            int s0 = col_idx[i];
            uint v0 = *(const uint*)&xb[(size_t)s0 * 128 + c];
            a0 += bf2f((ushort)(v0 & 0xffff)); a1 += bf2f((ushort)(v0 >> 16));
        }
        ushort2 o;
        o.x = f2bf((a0 + b0) * inv); o.y = f2bf((a1 + b1) * inv);
        *(ushort2*)&outb[(size_t)node * 128 + c] = o;
    }
}

// ---------------- dual MFMA GEMM ----------------
// C[M,256] = relu?( A1[M,K]@W1 + A2[M,K]@W2 + bias ), A bf16 [M,K], W bf16 [256,K].
// BM=64 x BN=256, BK=32, 256 thr (4 waves); wave w owns rows [w*16, w*16+16).
__global__ __launch_bounds__(256) void gemm_dual_mfma(
    const ushort* __restrict__ A1, const ushort* __restrict__ W1t,
    const ushort* __restrict__ A2, const ushort* __restrict__ W2t,
    const float* __restrict__ bias, ushort* __restrict__ out_bf,
    float* __restrict__ out_f32, int M, int K, int relu)
{
    __shared__ __align__(16) ushort As[4 * 64 * 8];
    __shared__ __align__(16) ushort Bs[4 * 256 * 8];
    int tid = threadIdx.x;
    int w = tid >> 6;
    int lane = tid & 63;
    int row0 = blockIdx.x * 64;

    floatx4 acc[16];
#pragma unroll
    for (int t = 0; t < 16; ++t) acc[t] = (floatx4){0.f, 0.f, 0.f, 0.f};

    int arow = row0 + lane;
    if (arow >= M) arow = M - 1;
    int ncol = w * 64 + lane;

    int m_ = lane & 15;
    int ko = lane >> 4;

    for (int mm = 0; mm < 2; ++mm) {
        const ushort* __restrict__ A = mm ? A2 : A1;
        const ushort* __restrict__ W = mm ? W2t : W1t;
        for (int k0 = 0; k0 < K; k0 += 32) {
            __builtin_amdgcn_global_load_lds(
                (const AS1 uint*)&A[(size_t)arow * K + k0 + w * 8],
                (AS3 uint*)&As[w * 512], 16, 0, 0);
#pragma unroll
            for (int j = 0; j < 4; ++j) {
                __builtin_amdgcn_global_load_lds(
                    (const AS1 uint*)&W[(size_t)ncol * K + k0 + j * 8],
                    (AS3 uint*)&Bs[(j * 256 + w * 64) * 8], 16, 0, 0);
            }
            __syncthreads();
            short8 af = *(const short8*)&As[(ko * 64 + w * 16 + m_) * 8];
#pragma unroll
            for (int t = 0; t < 16; ++t) {
                short8 bf = *(const short8*)&Bs[(ko * 256 + t * 16 + m_) * 8];
                acc[t] = __builtin_amdgcn_mfma_f32_16x16x32_bf16(af, bf, acc[t], 0, 0, 0);
            }
            __syncthreads();
        }
    }

    int mq = lane >> 4;
#pragma unroll
    for (int t = 0; t < 16; ++t) {
        int col = t * 16 + m_;
        float bv = bias[col];
#pragma unroll
        for (int r = 0; r < 4; ++r) {
            int row = row0 + w * 16 + mq * 4 + r;
            if (row >= M) continue;
            float v = acc[t][r] + bv;
            if (relu) v = fmaxf(v, 0.f);
            if (out_f32) out_f32[(size_t)row * 256 + col] = v;
            else         out_bf[(size_t)row * 256 + col] = f2bf(v);
        }
    }
}

// ---------------- launch ----------------

extern "C" void kernel_launch(void* const* d_in, const int* in_sizes, int n_in,
                              void* d_out, int out_size, void* d_ws, size_t ws_size,
                              hipStream_t stream) {
    const float* x    = (const float*)d_in[0];
    const float* W_l0 = (const float*)d_in[1];
    const float* b_l0 = (const float*)d_in[2];
    const float* W_r0 = (const float*)d_in[3];
    const float* W_l1 = (const float*)d_in[4];
    const float* b_l1 = (const float*)d_in[5];
    const float* W_r1 = (const float*)d_in[6];
    const float* W_l2 = (const float*)d_in[7];
    const float* b_l2 = (const float*)d_in[8];
    const float* W_r2 = (const float*)d_in[9];
    const int* esrc   = (const int*)d_in[10];
    const int* edst   = (const int*)d_in[11];
    float* out = (float*)d_out;

    size_t off = 0;
    char* ws = (char*)d_ws;
    auto take = [&](size_t bytes) -> void* {
        void* p = ws + off;
        off += (bytes + 255) & ~(size_t)255;
        return p;
    };
    int*    cnt     = (int*)take((size_t)N_NODES * 4);
    int*    row_ptr = (int*)take((size_t)(N_NODES + 1) * 4);
    int*    col_idx = (int*)take((size_t)N_EDGES * 4);
    int*    bsum    = (int*)take((size_t)SCAN_BLOCKS * 4);
    ushort* xb      = (ushort*)take((size_t)N_NODES * 128 * 2);
    ushort* Wl0t    = (ushort*)take((size_t)256 * 128 * 2);
    ushort* Wr0t    = (ushort*)take((size_t)256 * 128 * 2);
    ushort* Wl1t    = (ushort*)take((size_t)256 * 256 * 2);
    ushort* Wr1t    = (ushort*)take((size_t)256 * 256 * 2);
    ushort* Wl2t    = (ushort*)take((size_t)256 * 256 * 2);
    ushort* Wr2t    = (ushort*)take((size_t)256 * 256 * 2);
    ushort* aggrb   = (ushort*)take((size_t)N_NODES * 256 * 2);
    ushort* ha      = (ushort*)take((size_t)N_NODES * 256 * 2);
    ushort* hb      = (ushort*)take((size_t)N_NODES * 256 * 2);
    (void)ws_size; (void)in_sizes; (void)n_in; (void)out_size;

    // CSR (hierarchical scan)
    hipMemsetAsync(cnt, 0, (size_t)N_NODES * 4, stream);
    int eb = (N_EDGES + 255) / 256;
    count_edges<<<eb, 256, 0, stream>>>(edst, cnt);
    scan_partial<<<SCAN_BLOCKS, SCAN_T, 0, stream>>>(cnt, bsum, N_NODES);
    scan_block_sums<<<1, SCAN_T, 0, stream>>>(bsum);
    scan_fill<<<SCAN_BLOCKS, SCAN_T, 0, stream>>>(cnt, bsum, row_ptr, N_NODES);
    fill_csr<<<eb, 256, 0, stream>>>(esrc, edst, cnt, col_idx);

    // conversions
    int n4 = (N_NODES * 128) / 4;
    convert_x_bf16<<<(n4 + 255) / 256, 256, 0, stream>>>(x, xb, n4);
    transpose_w_bf16<<<(256 * 128 + 255) / 256, 256, 0, stream>>>(W_l0, Wl0t, 7);
    transpose_w_bf16<<<(256 * 128 + 255) / 256, 256, 0, stream>>>(W_r0, Wr0t, 7);
    transpose_w_bf16<<<(256 * 256 + 255) / 256, 256, 0, stream>>>(W_l1, Wl1t, 8);
    transpose_w_bf16<<<(256 * 256 + 255) / 256, 256, 0, stream>>>(W_r1, Wr1t, 8);
    transpose_w_bf16<<<(256 * 256 + 255) / 256, 256, 0, stream>>>(W_l2, Wl2t, 8);
    transpose_w_bf16<<<(256 * 256 + 255) / 256, 256, 0, stream>>>(W_r2, Wr2t, 8);

    dim3 ggrid((N_NODES + 63) / 64, 1);

    // layer 0: 128 -> 256, relu
    aggregate_bf16<<<N_NODES, 64, 0, stream>>>(xb, row_ptr, col_idx, aggrb, 128);
    gemm_dual_mfma<<<ggrid, 256, 0, stream>>>(aggrb, Wl0t, xb, Wr0t, b_l0,
                                              ha, nullptr, N_NODES, 128, 1);
    // layer 1: 256 -> 256, relu
    aggregate_bf16<<<N_NODES, 64, 0, stream>>>(ha, row_ptr, col_idx, aggrb, 256);
    gemm_dual_mfma<<<ggrid, 256, 0, stream>>>(aggrb, Wl1t, ha, Wr1t, b_l1,
                                              hb, nullptr, N_NODES, 256, 1);
    // layer 2: 256 -> 256, no relu, fp32 out
    aggregate_bf16<<<N_NODES, 64, 0, stream>>>(hb, row_ptr, col_idx, aggrb, 256);
    gemm_dual_mfma<<<ggrid, 256, 0, stream>>>(aggrb, Wl2t, hb, Wr2t, b_l2,
                                              nullptr, out, N_NODES, 256, 0);
}